// Round 5
// baseline (328.391 us; speedup 1.0000x reference)
//
#include <hip/hip_runtime.h>
#include <stdint.h>

#define BB 64
#define PP 24656
#define CC 81
#define NEGPOS 3
#define ROWS (BB * PP)            // 1,577,984
#define NSLOT 256

typedef unsigned int u32;
typedef unsigned long long u64;

// ws layout:
//   [0]      double csel
//   [64]     int num_pos[64]
//   [512]    double acc[NSLOT*3]
//   [8192]   float mine[ROWS]

// ---------------- k_main: pure streaming lse/diff, one 8-lane group per row,
// no LDS, registers only, 32 waves/CU ----------------
__global__ __launch_bounds__(256, 8) void k_main(
    const float* __restrict__ conf_data,
    const int*   __restrict__ conf_t,
    float* __restrict__ mine)
{
    const int t = threadIdx.x;
    const int sub = t & 7;                        // lane within 8-lane row group
    const long g0 = (long)blockIdx.x * 32 + (t >> 3);
    const long G = (long)gridDim.x * 32;          // 65536 row groups

    const int sbase = sub * 10;                   // segment start within row
    int tc_cur = conf_t[g0];                      // g0 < ROWS always

    for (long i = g0; i < ROWS; i += G) {
        // prefetch next row's target class (used next iteration)
        const long inx = i + G;
        int tc_nxt = 0;
        if (inx < ROWS) tc_nxt = conf_t[inx];

        const float* rp = conf_data + i * CC + sbase;
        float v[11];
        #pragma unroll
        for (int j = 0; j < 10; ++j) v[j] = rp[j];
        v[10] = (sub == 7) ? rp[10] : -1e30f;     // exp(-1e30) == 0

        float s = 0.0f;
        #pragma unroll
        for (int j = 0; j < 11; ++j) s += __expf(v[j]);

        // gather conf_data[i*CC + tc]: owner lane selects, others contribute 0
        const int jj = tc_cur - sbase;
        float cat = 0.0f;
        #pragma unroll
        for (int j = 0; j < 10; ++j) cat = (jj == j) ? v[j] : cat;
        cat = (jj == 10 && sub == 7) ? v[10] : cat;

        // reduce sum-of-exp and cat across the 8-lane group
        #pragma unroll
        for (int d = 1; d < 8; d <<= 1) {
            s   += __shfl_xor(s,   d, 64);
            cat += __shfl_xor(cat, d, 64);
        }

        if (sub == 0)
            mine[i] = fmaxf(__logf(s) - cat, 0.0f);   // lse - conf_at_t >= 0

        tc_cur = tc_nxt;
    }
}

// ---------------- k_pos: handle the ~2% positive rows; zero their mine entry
// so k_select's unsigned ordering excludes them ----------------
__global__ __launch_bounds__(256) void k_pos(
    const float* __restrict__ loc_data,
    const float* __restrict__ occ_data,
    const float* __restrict__ loc_t,
    const int*   __restrict__ conf_t,
    const float* __restrict__ occ_t,
    float* __restrict__ mine,
    double* __restrict__ acc,     // NSLOT*3
    int* __restrict__ num_pos)    // 64
{
    __shared__ double red[4][3];
    const int t = threadIdx.x;
    const int w = t >> 6;
    const int lane = t & 63;
    const int tid = blockIdx.x * 256 + t;
    const int nthr = gridDim.x * 256;
    const int nchunk = ROWS / 4;                 // 394,496 exactly

    double a_l = 0.0, a_o = 0.0, a_cp = 0.0;

    for (int c = tid; c < nchunk; c += nthr) {
        const int4 tc4 = ((const int4*)conf_t)[c];
        #pragma unroll
        for (int e = 0; e < 4; ++e) {
            const int tc = (e == 0) ? tc4.x : (e == 1) ? tc4.y : (e == 2) ? tc4.z : tc4.w;
            if (tc > 0) {
                const long i = (long)c * 4 + e;
                a_cp += (double)mine[i];
                mine[i] = 0.0f;                  // exclude from negative mining
                const float4 ld4 = *(const float4*)(loc_data + i * 4);
                const float4 lt4 = *(const float4*)(loc_t + i * 4);
                float sl = 0.0f;
                { float d = ld4.x - lt4.x, ad = fabsf(d); sl += (ad < 1.f) ? 0.5f*d*d : ad - 0.5f; }
                { float d = ld4.y - lt4.y, ad = fabsf(d); sl += (ad < 1.f) ? 0.5f*d*d : ad - 0.5f; }
                { float d = ld4.z - lt4.z, ad = fabsf(d); sl += (ad < 1.f) ? 0.5f*d*d : ad - 0.5f; }
                { float d = ld4.w - lt4.w, ad = fabsf(d); sl += (ad < 1.f) ? 0.5f*d*d : ad - 0.5f; }
                a_l += (double)sl;
                const float ot = occ_t[i];
                if (ot != -1.0f) { const float dd = occ_data[i] - ot; a_o += (double)(dd * dd); }
                atomicAdd(&num_pos[(int)(i / PP)], 1);
            }
        }
    }

    #pragma unroll
    for (int d = 1; d < 64; d <<= 1) {
        a_l  += __shfl_xor(a_l,  d, 64);
        a_o  += __shfl_xor(a_o,  d, 64);
        a_cp += __shfl_xor(a_cp, d, 64);
    }
    if (lane == 0) { red[w][0] = a_l; red[w][1] = a_o; red[w][2] = a_cp; }
    __syncthreads();
    if (t == 0) {
        double x0 = red[0][0] + red[1][0] + red[2][0] + red[3][0];
        double x1 = red[0][1] + red[1][1] + red[2][1] + red[3][1];
        double x2 = red[0][2] + red[1][2] + red[2][2] + red[3][2];
        const int slot = blockIdx.x & (NSLOT - 1);
        atomicAdd(&acc[slot * 3 + 0], x0);
        atomicAdd(&acc[slot * 3 + 1], x1);
        atomicAdd(&acc[slot * 3 + 2], x2);
    }
}

// ---------------- k_select: per batch row, radix-select k-th largest via
// ballot-match aggregated histograms; values register-resident ----------------
__global__ __launch_bounds__(1024) void k_select(
    const float* __restrict__ mine,
    const int* __restrict__ num_pos,
    double* __restrict__ csel)
{
    __shared__ u32 hist[256];
    __shared__ u32 sh_prefix, sh_kk;
    __shared__ double dred[16];
    __shared__ u32 cred[16];

    const int b = blockIdx.x;
    const int t = threadIdx.x;
    const int w = t >> 6;
    const int lane = t & 63;
    const float* row = mine + (long)b * PP;

    u32 u[25];
    #pragma unroll
    for (int r = 0; r < 25; ++r) {
        const int idx = t + (r << 10);
        u[r] = (idx < PP) ? __float_as_uint(row[idx]) : 0u;  // +0.0 pads sort last
    }

    const int np = num_pos[b];
    int k = NEGPOS * np;
    if (k > PP - 1) k = PP - 1;
    if (k <= 0) return;   // uniform across block

    u32 prefix = 0, mask = 0, kk = (u32)k;

    for (int pass = 0; pass < 4; ++pass) {
        const int shift = 24 - 8 * pass;
        if (t < 256) hist[t] = 0;
        __syncthreads();
        #pragma unroll
        for (int r = 0; r < 25; ++r) {
            const u32 uu = u[r];
            const bool valid = (uu & mask) == prefix;
            const u32 bin = (uu >> shift) & 255u;
            u64 eq = __ballot(valid);
            #pragma unroll
            for (int bi = 0; bi < 8; ++bi) {
                const u64 bal = __ballot((bin >> bi) & 1u);
                eq &= ((bin >> bi) & 1u) ? bal : ~bal;
            }
            if (valid && ((int)__ffsll(eq) - 1 == lane))
                atomicAdd(&hist[bin], (u32)__popcll(eq));
        }
        __syncthreads();
        if (t < 256) {
            u32 above = 0;
            for (int bb = t + 1; bb < 256; ++bb) above += hist[bb];
            if (above < kk && above + hist[t] >= kk) {   // exactly one bin
                sh_prefix = prefix | ((u32)t << shift);
                sh_kk = kk - above;
            }
        }
        __syncthreads();
        prefix = sh_prefix;
        kk = sh_kk;
        mask |= (0xFFu << shift);
        __syncthreads();
    }

    const u32 thr_bits = prefix;
    const float thr = __uint_as_float(thr_bits);

    double ssum = 0.0;
    u32 cnt = 0;
    #pragma unroll
    for (int r = 0; r < 25; ++r) {
        const u32 uu = u[r];
        if (uu > thr_bits) { ssum += (double)__uint_as_float(uu); cnt++; }
    }
    #pragma unroll
    for (int d = 1; d < 64; d <<= 1) {
        ssum += __shfl_xor(ssum, d, 64);
        cnt  += __shfl_xor(cnt,  d, 64);
    }
    if (lane == 0) { dred[w] = ssum; cred[w] = cnt; }
    __syncthreads();
    if (t == 0) {
        double S = 0.0; u32 cg = 0;
        #pragma unroll
        for (int j = 0; j < 16; ++j) { S += dred[j]; cg += cred[j]; }
        S += (double)(k - (int)cg) * (double)thr;   // ties at threshold value
        atomicAdd(csel, S);
    }
}

__global__ __launch_bounds__(256) void k_final(
    const double* __restrict__ acc,
    const double* __restrict__ csel,
    const int* __restrict__ num_pos,
    float* __restrict__ out)
{
    __shared__ double red[4][4];
    const int t = threadIdx.x;
    const int w = t >> 6;
    const int lane = t & 63;

    double l = acc[t * 3 + 0];
    double o = acc[t * 3 + 1];
    double c = acc[t * 3 + 2];
    double npd = (t < BB) ? (double)num_pos[t] : 0.0;
    #pragma unroll
    for (int d = 1; d < 64; d <<= 1) {
        l   += __shfl_xor(l,   d, 64);
        o   += __shfl_xor(o,   d, 64);
        c   += __shfl_xor(c,   d, 64);
        npd += __shfl_xor(npd, d, 64);
    }
    if (lane == 0) { red[w][0] = l; red[w][1] = o; red[w][2] = c; red[w][3] = npd; }
    __syncthreads();
    if (t == 0) {
        double L = 0, O = 0, Cp = 0, N = 0;
        #pragma unroll
        for (int j = 0; j < 4; ++j) { L += red[j][0]; O += red[j][1]; Cp += red[j][2]; N += red[j][3]; }
        out[0] = (float)(L / N);
        out[1] = (float)((Cp + csel[0]) / N);
        out[2] = (float)(O / N);
    }
}

extern "C" void kernel_launch(void* const* d_in, const int* in_sizes, int n_in,
                              void* d_out, int out_size, void* d_ws, size_t ws_size,
                              hipStream_t stream) {
    const float* loc_data  = (const float*)d_in[0];
    const float* conf_data = (const float*)d_in[1];
    const float* occ_data  = (const float*)d_in[2];
    const float* loc_t     = (const float*)d_in[3];
    const int*   conf_t    = (const int*)d_in[4];
    const float* occ_t     = (const float*)d_in[5];

    char* ws = (char*)d_ws;
    double* csel   = (double*)ws;            // 1 double
    int*    numpos = (int*)(ws + 64);        // 64 ints
    double* acc    = (double*)(ws + 512);    // NSLOT*3 doubles
    float*  mine   = (float*)(ws + 8192);    // ROWS floats

    hipMemsetAsync(ws, 0, 8192, stream);

    k_main<<<2048, 256, 0, stream>>>(conf_data, conf_t, mine);
    k_pos<<<512, 256, 0, stream>>>(loc_data, occ_data, loc_t, conf_t, occ_t,
                                   mine, acc, numpos);
    k_select<<<BB, 1024, 0, stream>>>(mine, numpos, csel);
    k_final<<<1, 256, 0, stream>>>(acc, csel, numpos, (float*)d_out);
}

// Round 6
// 298.072 us; speedup vs baseline: 1.1017x; 1.1017x over previous
//
#include <hip/hip_runtime.h>
#include <stdint.h>

#define BB 64
#define PP 24656
#define CC 81
#define NEGPOS 3
#define RPT 16                     // rows per wave tile
#define TFLT (RPT * CC)            // 1296 floats = 5184 B = 324 float4
#define NT ((BB * PP) / RPT)       // 98624 tiles exactly
#define TPB (PP / RPT)             // 1541 tiles per batch row exactly
#define ROWS (BB * PP)
#define NSLOT 256
#define NBLK 1536                  // 6 blocks/CU target

typedef unsigned int u32;
typedef unsigned long long u64;

// ws layout:
//   [0]      double csel
//   [64]     int num_pos[64]
//   [512]    double acc[NSLOT*3]   (l, o, cp)
//   [8192]   float mine[ROWS]

// load tile tdx into register set bn (7 VMEM ops, no waits here)
#define LOADT(bn, tdx) do { \
    const float4* gb = (const float4*)(conf_data + (long)(tdx) * TFLT); \
    _Pragma("unroll") \
    for (int c = 0; c < 5; ++c) buf##bn[c] = gb[c * 64 + lane]; \
    if (lane < 4) tail##bn = gb[320 + lane]; \
    if (s == 0) tc##bn = conf_t[(tdx) * RPT + r]; \
} while (0)

// stage registers->LDS slice, then compute rows (no VMEM reads consumed here)
#define STEP(bn, tdx) do { \
    asm volatile("s_waitcnt lgkmcnt(0)" ::: "memory"); \
    float4* sl4 = (float4*)slice; \
    _Pragma("unroll") \
    for (int c = 0; c < 5; ++c) sl4[c * 64 + lane] = buf##bn[c]; \
    if (lane < 4) sl4[320 + lane] = tail##bn; \
    asm volatile("s_waitcnt lgkmcnt(0)" ::: "memory"); \
    const float* rp = slice + r * CC; \
    const int start = (s == 0) ? 0 : (s * 20 + 1); \
    float sum = (s == 0) ? __expf(rp[20]) : 0.0f; \
    _Pragma("unroll") \
    for (int j = 0; j < 20; ++j) sum += __expf(rp[start + j]); \
    sum += __shfl_xor(sum, 1, 64); \
    sum += __shfl_xor(sum, 2, 64); \
    bool pos = false; \
    if (s == 0) { \
        const long i = (long)(tdx) * RPT + r; \
        const float cat = rp[tc##bn]; \
        const float diff = __logf(sum) - cat; \
        pos = tc##bn > 0; \
        a_cp += pos ? (double)diff : 0.0; \
        mine[i] = pos ? 0.0f : fmaxf(diff, 0.0f); \
    } \
    const u64 bal = __ballot(pos); \
    if (bal != 0ull && lane == 0) \
        atomicAdd(&num_pos[(tdx) / TPB], (int)__popcll(bal)); \
} while (0)

__global__ __launch_bounds__(256, 6) void k_main(
    const float* __restrict__ conf_data,
    const int*   __restrict__ conf_t,
    float* __restrict__ mine,
    double* __restrict__ acc,     // NSLOT*3
    int* __restrict__ num_pos)    // 64
{
    __shared__ __align__(16) float tile[4 * TFLT];   // 20736 B
    __shared__ double red[4];

    const int t = threadIdx.x;
    const int w = t >> 6;
    const int lane = t & 63;
    const int r = lane >> 2;        // row within tile 0..15
    const int s = lane & 3;         // quarter-row segment
    float* slice = tile + w * TFLT;
    const int wave_id = blockIdx.x * 4 + w;
    const int n_waves = NBLK * 4;

    double a_cp = 0.0;

    float4 bufA[5], bufB[5];
    float4 tailA, tailB;
    int tcA = 0, tcB = 0;

    int td = wave_id;
    LOADT(A, td);
    while (true) {
        int t2 = td + n_waves;
        if (t2 < NT) LOADT(B, t2);
        STEP(A, td);
        if (t2 >= NT) break;
        td = t2;
        t2 = td + n_waves;
        if (t2 < NT) LOADT(A, t2);
        STEP(B, td);
        if (t2 >= NT) break;
        td = t2;
    }

    #pragma unroll
    for (int d = 1; d < 64; d <<= 1) a_cp += __shfl_xor(a_cp, d, 64);
    if (lane == 0) red[w] = a_cp;
    __syncthreads();
    if (t == 0) {
        const double x = red[0] + red[1] + red[2] + red[3];
        atomicAdd(&acc[(blockIdx.x & (NSLOT - 1)) * 3 + 2], x);
    }
}

// ---------------- k_pos: loc smooth-L1 + occlusion MSE for positive rows ----
__global__ __launch_bounds__(256) void k_pos(
    const float* __restrict__ loc_data,
    const float* __restrict__ occ_data,
    const float* __restrict__ loc_t,
    const int*   __restrict__ conf_t,
    const float* __restrict__ occ_t,
    double* __restrict__ acc)     // NSLOT*3
{
    __shared__ double red[4][2];
    const int t = threadIdx.x;
    const int w = t >> 6;
    const int lane = t & 63;
    const int tid = blockIdx.x * 256 + t;
    const int nthr = gridDim.x * 256;
    const int nchunk = ROWS / 4;

    double a_l = 0.0, a_o = 0.0;

    for (int c = tid; c < nchunk; c += nthr) {
        const int4 tc4 = ((const int4*)conf_t)[c];
        #pragma unroll
        for (int e = 0; e < 4; ++e) {
            const int tc = (e == 0) ? tc4.x : (e == 1) ? tc4.y : (e == 2) ? tc4.z : tc4.w;
            if (tc > 0) {
                const long i = (long)c * 4 + e;
                const float4 ld4 = *(const float4*)(loc_data + i * 4);
                const float4 lt4 = *(const float4*)(loc_t + i * 4);
                float sl = 0.0f;
                { float d = ld4.x - lt4.x, ad = fabsf(d); sl += (ad < 1.f) ? 0.5f*d*d : ad - 0.5f; }
                { float d = ld4.y - lt4.y, ad = fabsf(d); sl += (ad < 1.f) ? 0.5f*d*d : ad - 0.5f; }
                { float d = ld4.z - lt4.z, ad = fabsf(d); sl += (ad < 1.f) ? 0.5f*d*d : ad - 0.5f; }
                { float d = ld4.w - lt4.w, ad = fabsf(d); sl += (ad < 1.f) ? 0.5f*d*d : ad - 0.5f; }
                a_l += (double)sl;
                const float ot = occ_t[i];
                if (ot != -1.0f) { const float dd = occ_data[i] - ot; a_o += (double)(dd * dd); }
            }
        }
    }

    #pragma unroll
    for (int d = 1; d < 64; d <<= 1) {
        a_l += __shfl_xor(a_l, d, 64);
        a_o += __shfl_xor(a_o, d, 64);
    }
    if (lane == 0) { red[w][0] = a_l; red[w][1] = a_o; }
    __syncthreads();
    if (t == 0) {
        const double x0 = red[0][0] + red[1][0] + red[2][0] + red[3][0];
        const double x1 = red[0][1] + red[1][1] + red[2][1] + red[3][1];
        const int slot = blockIdx.x & (NSLOT - 1);
        atomicAdd(&acc[slot * 3 + 0], x0);
        atomicAdd(&acc[slot * 3 + 1], x1);
    }
}

// ---------------- k_select: radix k-th largest via ballot-match histogram ----
__global__ __launch_bounds__(1024) void k_select(
    const float* __restrict__ mine,
    const int* __restrict__ num_pos,
    double* __restrict__ csel)
{
    __shared__ u32 hist[256];
    __shared__ u32 sh_prefix, sh_kk;
    __shared__ double dred[16];
    __shared__ u32 cred[16];

    const int b = blockIdx.x;
    const int t = threadIdx.x;
    const int w = t >> 6;
    const int lane = t & 63;
    const float* row = mine + (long)b * PP;

    u32 u[25];
    #pragma unroll
    for (int r = 0; r < 25; ++r) {
        const int idx = t + (r << 10);
        u[r] = (idx < PP) ? __float_as_uint(row[idx]) : 0u;  // +0.0 pads sort last
    }

    const int np = num_pos[b];
    int k = NEGPOS * np;
    if (k > PP - 1) k = PP - 1;
    if (k <= 0) return;   // uniform across block

    u32 prefix = 0, mask = 0, kk = (u32)k;

    for (int pass = 0; pass < 4; ++pass) {
        const int shift = 24 - 8 * pass;
        if (t < 256) hist[t] = 0;
        __syncthreads();
        #pragma unroll
        for (int r = 0; r < 25; ++r) {
            const u32 uu = u[r];
            const bool valid = (uu & mask) == prefix;
            const u32 bin = (uu >> shift) & 255u;
            u64 eq = __ballot(valid);
            #pragma unroll
            for (int bi = 0; bi < 8; ++bi) {
                const u64 bal = __ballot((bin >> bi) & 1u);
                eq &= ((bin >> bi) & 1u) ? bal : ~bal;
            }
            if (valid && ((int)__ffsll(eq) - 1 == lane))
                atomicAdd(&hist[bin], (u32)__popcll(eq));
        }
        __syncthreads();
        if (t < 256) {
            u32 above = 0;
            for (int bb = t + 1; bb < 256; ++bb) above += hist[bb];
            if (above < kk && above + hist[t] >= kk) {   // exactly one bin
                sh_prefix = prefix | ((u32)t << shift);
                sh_kk = kk - above;
            }
        }
        __syncthreads();
        prefix = sh_prefix;
        kk = sh_kk;
        mask |= (0xFFu << shift);
        __syncthreads();
    }

    const u32 thr_bits = prefix;
    const float thr = __uint_as_float(thr_bits);

    double ssum = 0.0;
    u32 cnt = 0;
    #pragma unroll
    for (int r = 0; r < 25; ++r) {
        const u32 uu = u[r];
        if (uu > thr_bits) { ssum += (double)__uint_as_float(uu); cnt++; }
    }
    #pragma unroll
    for (int d = 1; d < 64; d <<= 1) {
        ssum += __shfl_xor(ssum, d, 64);
        cnt  += __shfl_xor(cnt,  d, 64);
    }
    if (lane == 0) { dred[w] = ssum; cred[w] = cnt; }
    __syncthreads();
    if (t == 0) {
        double S = 0.0; u32 cg = 0;
        #pragma unroll
        for (int j = 0; j < 16; ++j) { S += dred[j]; cg += cred[j]; }
        S += (double)(k - (int)cg) * (double)thr;   // ties at threshold value
        atomicAdd(csel, S);
    }
}

__global__ __launch_bounds__(256) void k_final(
    const double* __restrict__ acc,
    const double* __restrict__ csel,
    const int* __restrict__ num_pos,
    float* __restrict__ out)
{
    __shared__ double red[4][4];
    const int t = threadIdx.x;
    const int w = t >> 6;
    const int lane = t & 63;

    double l = acc[t * 3 + 0];
    double o = acc[t * 3 + 1];
    double c = acc[t * 3 + 2];
    double npd = (t < BB) ? (double)num_pos[t] : 0.0;
    #pragma unroll
    for (int d = 1; d < 64; d <<= 1) {
        l   += __shfl_xor(l,   d, 64);
        o   += __shfl_xor(o,   d, 64);
        c   += __shfl_xor(c,   d, 64);
        npd += __shfl_xor(npd, d, 64);
    }
    if (lane == 0) { red[w][0] = l; red[w][1] = o; red[w][2] = c; red[w][3] = npd; }
    __syncthreads();
    if (t == 0) {
        double L = 0, O = 0, Cp = 0, N = 0;
        #pragma unroll
        for (int j = 0; j < 4; ++j) { L += red[j][0]; O += red[j][1]; Cp += red[j][2]; N += red[j][3]; }
        out[0] = (float)(L / N);
        out[1] = (float)((Cp + csel[0]) / N);
        out[2] = (float)(O / N);
    }
}

extern "C" void kernel_launch(void* const* d_in, const int* in_sizes, int n_in,
                              void* d_out, int out_size, void* d_ws, size_t ws_size,
                              hipStream_t stream) {
    const float* loc_data  = (const float*)d_in[0];
    const float* conf_data = (const float*)d_in[1];
    const float* occ_data  = (const float*)d_in[2];
    const float* loc_t     = (const float*)d_in[3];
    const int*   conf_t    = (const int*)d_in[4];
    const float* occ_t     = (const float*)d_in[5];

    char* ws = (char*)d_ws;
    double* csel   = (double*)ws;            // 1 double
    int*    numpos = (int*)(ws + 64);        // 64 ints
    double* acc    = (double*)(ws + 512);    // NSLOT*3 doubles
    float*  mine   = (float*)(ws + 8192);    // ROWS floats

    hipMemsetAsync(ws, 0, 8192, stream);

    k_main<<<NBLK, 256, 0, stream>>>(conf_data, conf_t, mine, acc, numpos);
    k_pos<<<512, 256, 0, stream>>>(loc_data, occ_data, loc_t, conf_t, occ_t, acc);
    k_select<<<BB, 1024, 0, stream>>>(mine, numpos, csel);
    k_final<<<1, 256, 0, stream>>>(acc, csel, numpos, (float*)d_out);
}